// Round 1
// baseline (56.603 us; speedup 1.0000x reference)
//
#include <hip/hip_runtime.h>

// YIN pitch estimator, B=8, n=80000, fp32.
// SR=8000 HOP=80 TAU_MIN=20 TAU_MAX=133 W=133 FRAME_LEN=266 THRESH=0.2
// n_frames = 1+(80000-266)/80 = 997 ; output keeps frames 0..995 (996 per batch)

#define SR_I      8000
#define HOP       80
#define TAU_MIN   20
#define TAU_MAX   133
#define W_LEN     133
#define FRAME_LEN 266
#define NF_OUT    996
#define BATCH     8
#define NSAMP     80000
#define THRESH    0.2f

__global__ __launch_bounds__(192) void yin_kernel(const float* __restrict__ x,
                                                  float* __restrict__ out) {
    const int blk = blockIdx.x;
    const int b = blk / NF_OUT;
    const int f = blk - b * NF_OUT;
    const float* __restrict__ frame = x + (size_t)b * NSAMP + (size_t)f * HOP;

    __shared__ float sf[FRAME_LEN];
    __shared__ float sd[TAU_MAX + 1];

    const int t = threadIdx.x;

    // Stage frame into LDS (266 floats, 192 threads -> <=2 loads each).
    for (int i = t; i < FRAME_LEN; i += 192) sf[i] = frame[i];
    __syncthreads();

    // One thread per tau: d[tau] = sum_j (f[j] - f[tau+j])^2
    if (t <= TAU_MAX) {
        float acc = 0.0f;
        for (int j = 0; j < W_LEN; ++j) {
            float diff = sf[j] - sf[t + j];
            acc = fmaf(diff, diff, acc);
        }
        sd[t] = acc;
    }
    __syncthreads();

    // CMNDF scan + first-threshold-crossing pick (thread 0; break-free loop
    // so the compiler can batch the LDS reads ahead of the dependent adds).
    if (t == 0) {
        float cum = 0.0f;
        int tau = 0;
        for (int ta = 1; ta <= TAU_MAX; ++ta) {
            float dv = sd[ta];
            cum += dv;
            float cm = dv * (float)ta / fmaxf(cum, 1e-8f);
            if (tau == 0 && ta >= TAU_MIN && cm < THRESH) tau = ta;
        }
        float res = (tau > 0) ? ((float)SR_I / (float)tau) : 0.0f;
        out[(size_t)b * NF_OUT + f] = res;
    }
}

extern "C" void kernel_launch(void* const* d_in, const int* in_sizes, int n_in,
                              void* d_out, int out_size, void* d_ws, size_t ws_size,
                              hipStream_t stream) {
    (void)in_sizes; (void)n_in; (void)d_ws; (void)ws_size; (void)out_size;
    const float* x = (const float*)d_in[0];
    float* out = (float*)d_out;
    yin_kernel<<<dim3(BATCH * NF_OUT), dim3(192), 0, stream>>>(x, out);
}

// Round 2
// 21.736 us; speedup vs baseline: 2.6041x; 2.6041x over previous
//
#include <hip/hip_runtime.h>

// YIN pitch, B=8, n=80000, fp32.
// SR=8000 HOP=80 TAU_MIN=20 TAU_MAX=133 W=133 FRAME_LEN=266 THRESH=0.2
// n_frames=997, output keeps 996 per batch.
//
// v2: wave-per-frame (4 frames/block), lane l owns tau=l+1 and tau=l+65;
// taus 129..133 via j-split + butterfly reduce; CMNDF cumsum via shfl_up
// prefix scan in registers; candidate pick via ballot+ffs. No serial tail.

#define SR_F      8000.0f
#define HOP       80
#define TAU_MIN   20
#define W_LEN     133
#define FRAME_LEN 266
#define NF_OUT    996
#define NSAMP     80000
#define THRESH    0.2f
#define FPB       4
#define CHUNK     (FRAME_LEN + (FPB - 1) * HOP)   // 506 floats
#define BPB       (NF_OUT / FPB)                  // 249 blocks per batch

__global__ __launch_bounds__(256, 8) void yin_kernel(const float* __restrict__ x,
                                                     float* __restrict__ out) {
    const int bx = blockIdx.x;
    const int b  = bx / BPB;
    const int fb = bx - b * BPB;
    const int frame0 = fb * FPB;
    const float* __restrict__ xrow = x + (size_t)b * NSAMP + (size_t)frame0 * HOP;

    __shared__ float sch[CHUNK];
    const int t = threadIdx.x;
    for (int i = t; i < CHUNK; i += 256) sch[i] = xrow[i];
    __syncthreads();

    const int w    = t >> 6;       // wave id = frame within block
    const int lane = t & 63;
    const float* __restrict__ f   = sch + w * HOP;
    const float* __restrict__ fa  = f + lane + 1;    // tau_a = lane+1
    const float* __restrict__ fbp = f + lane + 65;   // tau_b = lane+65

    // ---- difference function, taus 1..128 (2 per lane, 2 chains each) ----
    float A0 = 0.f, A1 = 0.f, B0 = 0.f, B1 = 0.f;
    #pragma unroll 4
    for (int j = 0; j < 132; j += 2) {
        float b0 = f[j], b1 = f[j + 1];
        float d;
        d = b0 - fa[j];      A0 = fmaf(d, d, A0);
        d = b1 - fa[j + 1];  A1 = fmaf(d, d, A1);
        d = b0 - fbp[j];     B0 = fmaf(d, d, B0);
        d = b1 - fbp[j + 1]; B1 = fmaf(d, d, B1);
    }
    {   // j = 132 remainder
        float b0 = f[132];
        float d;
        d = b0 - fa[132];  A0 = fmaf(d, d, A0);
        d = b0 - fbp[132]; B0 = fmaf(d, d, B0);
    }
    float dA = A0 + A1;   // d[lane+1]
    float dB = B0 + B1;   // d[lane+65]

    // ---- taus 129..133: j split across lanes (j = lane, lane+64, lane+128<133) ----
    float p[5] = {0.f, 0.f, 0.f, 0.f, 0.f};
    {
        float base0 = f[lane];
        float base1 = f[lane + 64];
        const float* g0 = f + 129 + lane;
        const float* g1 = f + 129 + lane + 64;
        #pragma unroll
        for (int k = 0; k < 5; ++k) {
            float d0 = base0 - g0[k]; p[k] = fmaf(d0, d0, p[k]);
            float d1 = base1 - g1[k]; p[k] = fmaf(d1, d1, p[k]);
        }
        if (lane < 5) {
            float base2 = f[lane + 128];
            const float* g2 = f + 129 + lane + 128;
            #pragma unroll
            for (int k = 0; k < 5; ++k) {
                float d2 = base2 - g2[k]; p[k] = fmaf(d2, d2, p[k]);
            }
        }
    }
    #pragma unroll
    for (int k = 0; k < 5; ++k) {
        #pragma unroll
        for (int off = 32; off; off >>= 1) p[k] += __shfl_xor(p[k], off);
    }   // p[k] = d[129+k], uniform across wave

    // ---- CMNDF: inclusive prefix scan of d over lanes (registers only) ----
    float sA = dA, sB = dB;
    #pragma unroll
    for (int off = 1; off < 64; off <<= 1) {
        float uA = __shfl_up(sA, off);
        float uB = __shfl_up(sB, off);
        if (lane >= off) { sA += uA; sB += uB; }
    }
    float total0 = __shfl(sA, 63);          // cum[64]
    float cumA = sA;                        // cum[lane+1]
    float cumB = total0 + sB;               // cum[lane+65]
    float total1 = __shfl(cumB, 63);        // cum[128]

    float cmA = dA * (float)(lane + 1)  / fmaxf(cumA, 1e-8f);
    float cmB = dB * (float)(lane + 65) / fmaxf(cumB, 1e-8f);
    bool candA = (lane >= (TAU_MIN - 1)) && (cmA < THRESH);  // tau_a >= 20
    bool candB = (cmB < THRESH);                             // tau_b >= 65 always
    unsigned long long mA = __ballot(candA);
    unsigned long long mB = __ballot(candB);

    int tau = 0;
    if (mA) {
        tau = __ffsll((unsigned long long)mA);        // lane+1
    } else if (mB) {
        tau = __ffsll((unsigned long long)mB) + 64;   // lane+65
    } else {
        float c = total1;
        #pragma unroll
        for (int k = 0; k < 5; ++k) {
            c += p[k];
            float cm = p[k] * (float)(129 + k) / fmaxf(c, 1e-8f);
            if (tau == 0 && cm < THRESH) tau = 129 + k;
        }
    }

    if (lane == 0) {
        float f0v = (tau > 0) ? (SR_F / (float)tau) : 0.0f;
        out[(size_t)b * NF_OUT + frame0 + w] = f0v;
    }
}

extern "C" void kernel_launch(void* const* d_in, const int* in_sizes, int n_in,
                              void* d_out, int out_size, void* d_ws, size_t ws_size,
                              hipStream_t stream) {
    (void)in_sizes; (void)n_in; (void)d_ws; (void)ws_size; (void)out_size;
    const float* x = (const float*)d_in[0];
    float* out = (float*)d_out;
    yin_kernel<<<dim3(8 * BPB), dim3(256), 0, stream>>>(x, out);
}